// Round 1
// baseline (480.740 us; speedup 1.0000x reference)
//
#include <hip/hip_runtime.h>
#include <math.h>

#define D_FEAT 524288        // 512*32*32
#define NSAMP  128
#define NCLS   12
#define BK     256           // K elements staged in LDS per slice
#define KPB    2048          // K per block (8 slices of BK)
#define NB     256           // split-K blocks for the Gram kernel
#define D4     131072        // D_FEAT / 4

typedef __bf16 bf16x8 __attribute__((ext_vector_type(8)));
typedef float  f32x16 __attribute__((ext_vector_type(16)));

__device__ __forceinline__ unsigned pack_bf16(float a, float b) {
  // round-to-nearest-even fp32 -> bf16, packed low/high
  unsigned ua = __float_as_uint(a); ua += 0x7fffu + ((ua >> 16) & 1u);
  unsigned ub = __float_as_uint(b); ub += 0x7fffu + ((ub >> 16) & 1u);
  return (ua >> 16) | (ub & 0xffff0000u);
}

// ---------------------------------------------------------------------------
// Kernel 1: split-K Gram partials. Block b handles K range [b*KPB, (b+1)*KPB).
// LDS layout: 16-byte units; unit(s, g) at  g*128 + (s ^ (g&7))  holds bf16
// elements k=8g..8g+7 of sample s (XOR swizzle -> conflict-free writes+reads).
// 8 waves: wave w computes rows Ra=(w>>2)*64 .. +63, cols Ca=(w&3)*32 .. +31.
// ---------------------------------------------------------------------------
__global__ __launch_bounds__(512, 2) void gram_k(const float* __restrict__ f,
                                                 float* __restrict__ gram,
                                                 float* __restrict__ partial,
                                                 int atomic_mode) {
  __shared__ __align__(16) unsigned char lds[BK * NSAMP * 2];  // 64 KB
  const int t    = threadIdx.x;
  const int b    = blockIdx.x;
  const int wave = t >> 6;
  const int lane = t & 63;
  const int sl   = lane & 31;
  const int hi   = lane >> 5;
  const int Ra   = (wave >> 2) * 64;
  const int Ca   = (wave & 3) * 32;
  const int kq   = lane;            // float4 column within slice (0..63)
  const size_t k0 = (size_t)b * KPB;

  f32x16 acc0, acc1;
#pragma unroll
  for (int i = 0; i < 16; ++i) { acc0[i] = 0.f; acc1[i] = 0.f; }

  const int wg      = kq >> 1;      // staging kgroup
  const int halfsel = kq & 1;

  float4 pf[16];
  // preload + stage slice 0
#pragma unroll
  for (int i = 0; i < 16; ++i) {
    const int s = i * 8 + wave;
    pf[i] = *(const float4*)(f + (size_t)s * D_FEAT + k0 + kq * 4);
  }
#pragma unroll
  for (int i = 0; i < 16; ++i) {
    const int s = i * 8 + wave;
    uint2 p; p.x = pack_bf16(pf[i].x, pf[i].y); p.y = pack_bf16(pf[i].z, pf[i].w);
    *(uint2*)(lds + (size_t)(wg * NSAMP + (s ^ (wg & 7))) * 16 + halfsel * 8) = p;
  }

  for (int sli = 0; sli < KPB / BK; ++sli) {
    __syncthreads();  // staged data visible
    if (sli < KPB / BK - 1) {
      const size_t kb = k0 + (size_t)(sli + 1) * BK;
#pragma unroll
      for (int i = 0; i < 16; ++i) {
        const int s = i * 8 + wave;
        pf[i] = *(const float4*)(f + (size_t)s * D_FEAT + kb + kq * 4);
      }
    }
#pragma unroll
    for (int t16 = 0; t16 < 16; ++t16) {
      const int g = 2 * t16 + hi, gx = g & 7;
      const unsigned char* base = lds + g * (NSAMP * 16);
      bf16x8 a0 = *(const bf16x8*)(base + (((Ra      + sl) ^ gx) << 4));
      bf16x8 a1 = *(const bf16x8*)(base + (((Ra + 32 + sl) ^ gx) << 4));
      bf16x8 b0 = *(const bf16x8*)(base + (((Ca      + sl) ^ gx) << 4));
      acc0 = __builtin_amdgcn_mfma_f32_32x32x16_bf16(a0, b0, acc0, 0, 0, 0);
      acc1 = __builtin_amdgcn_mfma_f32_32x32x16_bf16(a1, b0, acc1, 0, 0, 0);
    }
    __syncthreads();  // all reads of this slice done
    if (sli < KPB / BK - 1) {
#pragma unroll
      for (int i = 0; i < 16; ++i) {
        const int s = i * 8 + wave;
        uint2 p; p.x = pack_bf16(pf[i].x, pf[i].y); p.y = pack_bf16(pf[i].z, pf[i].w);
        *(uint2*)(lds + (size_t)(wg * NSAMP + (s ^ (wg & 7))) * 16 + halfsel * 8) = p;
      }
    }
  }

  // epilogue: C/D layout col=lane&31, row=4*(lane>>5)+(reg&3)+8*(reg>>2)
  if (atomic_mode) {
#pragma unroll
    for (int r = 0; r < 16; ++r) {
      const int row0 = Ra + 4 * hi + (r & 3) + 8 * (r >> 2);
      atomicAdd(gram + row0 * NSAMP + Ca + sl, acc0[r]);
      atomicAdd(gram + (row0 + 32) * NSAMP + Ca + sl, acc1[r]);
    }
  } else {
    float* p = partial + (size_t)b * (NSAMP * NSAMP);
#pragma unroll
    for (int r = 0; r < 16; ++r) {
      const int row0 = Ra + 4 * hi + (r & 3) + 8 * (r >> 2);
      p[row0 * NSAMP + Ca + sl]        = acc0[r];
      p[(row0 + 32) * NSAMP + Ca + sl] = acc1[r];
    }
  }
}

// ---------------------------------------------------------------------------
// Kernel 1b: reduce NB partial Grams -> gram[128][128]
// ---------------------------------------------------------------------------
__global__ __launch_bounds__(256) void reduce_k(const float* __restrict__ partial,
                                                float* __restrict__ gram) {
  const int idx = blockIdx.x * 256 + threadIdx.x;  // 64 blocks -> 16384
  float s = 0.f;
#pragma unroll 8
  for (int b = 0; b < NB; ++b) s += partial[(size_t)b * (NSAMP * NSAMP) + idx];
  gram[idx] = s;
}

// ---------------------------------------------------------------------------
// Kernel 2: weights + class-sorted sample order (1 block, 128 threads)
// ---------------------------------------------------------------------------
__global__ void weights_k(const float* __restrict__ gram, const int* __restrict__ labels,
                          float* __restrict__ w_out, int* __restrict__ order_out,
                          int* __restrict__ off_out) {
  __shared__ float sq[NSAMP];
  __shared__ int   lab[NSAMP];
  __shared__ float wv[NSAMP];
  __shared__ float wsum_s;
  __shared__ int   cnt[NCLS];
  __shared__ int   off[NCLS + 1];
  const int t = threadIdx.x;
  lab[t] = labels[t];
  sq[t]  = gram[t * NSAMP + t];
  if (t < NCLS) cnt[t] = 0;
  __syncthreads();
  const int   myl = lab[t];
  const float st  = sq[t];
  float dsum = 0.f;
  for (int j = 0; j < NSAMP; ++j) {
    if (j != t && lab[j] == myl) {
      float d2 = st + sq[j] - 2.f * gram[t * NSAMP + j];
      if (d2 > 0.f) dsum += sqrtf(d2);
    }
  }
  const float wt = 1.f / (sqrtf(dsum * dsum + 25.f) + 1e-12f);
  wv[t] = wt;
  atomicAdd(&cnt[myl], 1);
  __syncthreads();
  if (t == 0) {
    float s = 0.f;
    for (int j = 0; j < NSAMP; ++j) s += wv[j];
    wsum_s = s;
    off[0] = 0;
    for (int c = 0; c < NCLS; ++c) off[c + 1] = off[c] + cnt[c];
  }
  __syncthreads();
  int rank = 0;
  for (int j = 0; j < t; ++j) rank += (lab[j] == myl) ? 1 : 0;
  const int pos  = off[myl] + rank;
  order_out[pos] = t;
  w_out[pos]     = wt / (wsum_s + 1e-12f);
  if (t <= NCLS) off_out[t] = off[t];
}

// ---------------------------------------------------------------------------
// Kernel 3: weighted class scatter-sum. One float4 column per thread,
// samples iterated in class-sorted order (uniform control flow, no dynamic
// accumulator indexing). Second full read of features.
// ---------------------------------------------------------------------------
__global__ __launch_bounds__(256) void scatter_k(const float* __restrict__ f,
                                                 const float* __restrict__ w,
                                                 const int* __restrict__ order,
                                                 const int* __restrict__ off,
                                                 float* __restrict__ out) {
  __shared__ float w_l[NSAMP];
  __shared__ int   ord_l[NSAMP];
  __shared__ int   off_l[NCLS + 1];
  const int t = threadIdx.x;
  if (t < NSAMP) { w_l[t] = w[t]; ord_l[t] = order[t]; }
  if (t <= NCLS) off_l[t] = off[t];
  __syncthreads();
  const size_t d4 = (size_t)blockIdx.x * 256 + t;
  const float4* f4 = (const float4*)f;
  float4* o4 = (float4*)out;
  for (int c = 0; c < NCLS; ++c) {
    float4 acc = make_float4(0.f, 0.f, 0.f, 0.f);
    const int e = off_l[c + 1];
#pragma unroll 4
    for (int j = off_l[c]; j < e; ++j) {
      const float  wj = w_l[j];
      const float4 v  = f4[(size_t)ord_l[j] * D4 + d4];
      acc.x += wj * v.x; acc.y += wj * v.y; acc.z += wj * v.z; acc.w += wj * v.w;
    }
    o4[(size_t)c * D4 + d4] = acc;
  }
}

extern "C" void kernel_launch(void* const* d_in, const int* in_sizes, int n_in,
                              void* d_out, int out_size, void* d_ws, size_t ws_size,
                              hipStream_t stream) {
  const float* f      = (const float*)d_in[0];
  const int*   labels = (const int*)d_in[1];
  float* out  = (float*)d_out;
  float* ws_f = (float*)d_ws;

  // ws layout (floats): [0,16384) gram | [16384,16512) w_sorted |
  // [16512,16640) order(int) | [16640,16656) cls_off(int) | [32768,...) partials
  float* gram     = ws_f;
  float* w_sorted = ws_f + 16384;
  int*   order    = (int*)(ws_f + 16384 + 128);
  int*   clsoff   = (int*)(ws_f + 16384 + 256);
  float* partial  = ws_f + 32768;

  const size_t need = (size_t)32768 * 4 + (size_t)NB * NSAMP * NSAMP * 4;  // ~16.9 MB
  const int atomic_mode = (ws_size < need) ? 1 : 0;

  if (atomic_mode) hipMemsetAsync(gram, 0, NSAMP * NSAMP * sizeof(float), stream);
  gram_k<<<NB, 512, 0, stream>>>(f, gram, partial, atomic_mode);
  if (!atomic_mode) reduce_k<<<64, 256, 0, stream>>>(partial, gram);
  weights_k<<<1, NSAMP, 0, stream>>>(gram, labels, w_sorted, order, clsoff);
  scatter_k<<<D4 / 256, 256, 0, stream>>>(f, w_sorted, order, clsoff, out);
}